// Round 10
// baseline (35.621 us; speedup 1.0000x reference)
//
#include <hip/hip_runtime.h>

typedef float v2f __attribute__((ext_vector_type(2)));

namespace {

constexpr int H = 128, W = 128, NPIX = H * W;
constexpr double GAMMA_Wd = 3.3257199;
constexpr float GAM2 = (float)(GAMMA_Wd * GAMMA_Wd);
constexpr float VBIG  = 1e30f;    // var' sentinel for var==0 (incl. OOB pad)
constexpr float NHUGE = -1e38f;   // d!=0 punishment

constexpr int TR = 4, TC = 16;
constexpr int HR = TR + 4, HC = TC + 4;   // 8 x 20
constexpr int NSITE = HR * HC;            // 160
constexpr int NK = 18;   // 9 guid*sqrt(sig/2) | 3 est | 3 var' | 3 noisy
constexpr int KP = 19;   // padded site stride in float4
constexpr int NTHR = 1024;                // 64 px x 16 column-slices (16 waves)

// slice s in [0,16) owns columns {s} and {s+16 if s<9} of the 25 (di,dj) offsets.

__global__ __launch_bounds__(NTHR)
__attribute__((amdgpu_waves_per_eu(4)))   // force VGPR<=128 so all 16 waves fit (4/SIMD)
void statden(const float4* __restrict__ noisy,
             const float4* __restrict__ guid,
             const float4* __restrict__ est,
             const float4* __restrict__ var,
             float4* __restrict__ out)
{
    __shared__ float4 halo[NSITE * KP];   // 48640 B; later reused as reduce scratch

    const int tid   = threadIdx.x;
    const int tiler = blockIdx.x >> 3;
    const int tilec = blockIdx.x & 7;
    const int r0 = tiler * TR - 2;
    const int c0 = tilec * TC - 2;

    // ---- stage halo (transforms folded in; zero-pad OOB == reference padding) ----
    for (int u = tid; u < NSITE * NK; u += NTHR) {
        const int k    = u / NSITE;
        const int site = u - k * NSITE;
        const int sr  = site / HC;
        const int scp = site - sr * HC;
        const int gr = r0 + sr;
        const int gc = c0 + scp;
        const bool varslot = (k >= 12) && (k < 15);
        float4 v;
        if (((unsigned)gr < (unsigned)H) && ((unsigned)gc < (unsigned)W)) {
            const int gpix = (gr << 7) + gc;
            if (k < 9) {
                // sqrt(sigma/2) folded: exp arg = 2*cross - qc~ - qj~
                const float sca = (k < 3) ? 0.22360679774997896f
                                : (k < 6) ? 5.0f
                                          : 2.2360679774997896f;
                const float4 g = guid[k * NPIX + gpix];
                v = make_float4(g.x * sca, g.y * sca, g.z * sca, g.w * sca);
            } else if (k < 12) {
                v = est[(k - 9) * NPIX + gpix];
            } else if (k < 15) {
                // var' = (var==0) ? -VBIG : gamma^2 * var
                const float4 w4 = var[(k - 12) * NPIX + gpix];
                v.x = (w4.x == 0.f) ? -VBIG : GAM2 * w4.x;
                v.y = (w4.y == 0.f) ? -VBIG : GAM2 * w4.y;
                v.z = (w4.z == 0.f) ? -VBIG : GAM2 * w4.z;
                v.w = (w4.w == 0.f) ? -VBIG : GAM2 * w4.w;
            } else {
                v = noisy[(k - 15) * NPIX + gpix];
            }
        } else {
            const float pad = varslot ? -VBIG : 0.f;
            v = make_float4(pad, pad, pad, pad);
        }
        halo[site * KP + k] = v;
    }
    __syncthreads();

    // ---- compute: thread = (pixel p, slice s) ----
    const int p  = tid & 63;
    const int s  = tid >> 6;              // 0..15, wave-uniform
    const int pr = p >> 4;
    const int pc = p & 15;

    const float4* cs = &halo[((pr + 2) * HC + (pc + 2)) * KP];

    // hoist ONLY the small center state (VGPR budget = 128):
    // nqc (4), eiP (12), viP (12); center guidance re-read from LDS per column.
    v2f nqc[2] = {{0.f, 0.f}, {0.f, 0.f}};   // -qc~
#pragma unroll
    for (int c = 0; c < 9; ++c) {
        const float4 g = cs[c];
        const v2f g01 = (v2f){g.x, g.y}, g23 = (v2f){g.z, g.w};
        nqc[0] -= g01 * g01;
        nqc[1] -= g23 * g23;
    }
    v2f eiP[3][2], viP[3][2];
#pragma unroll
    for (int c = 0; c < 3; ++c) {
        const float4 e = cs[9 + c];
        eiP[c][0] = (v2f){e.x, e.y}; eiP[c][1] = (v2f){e.z, e.w};
        const float4 w4 = cs[12 + c];
        viP[c][0] = (v2f){w4.x, w4.y}; viP[c][1] = (v2f){w4.z, w4.w};
    }

    v2f accP[3][2] = {};
    v2f denP[2] = {};

#pragma unroll
    for (int cc = 0; cc < 2; ++cc) {
        const int col = s + (cc << 4);
        if (col < 25) {                   // wave-uniform (cc=1 active iff s<9)
            const int di = col / 5 - 2;
            const int dj = col - (col / 5) * 5 - 2;
            const float4* js = &halo[((pr + 2 + di) * HC + (pc + 2 + dj)) * KP];

            // guidance quadratic (packed); gc re-read from LDS each channel
            v2f qj2[2] = {};
            v2f cr[4][2] = {};            // cross[tt][t-half]
#pragma unroll
            for (int c = 0; c < 9; ++c) {
                const float4 gcv = cs[c];
                const float4 g   = js[c];
                const v2f gc01 = (v2f){gcv.x, gcv.y}, gc23 = (v2f){gcv.z, gcv.w};
                const v2f g01  = (v2f){g.x, g.y},     g23  = (v2f){g.z, g.w};
                qj2[0] += g01 * g01;  qj2[1] += g23 * g23;
                cr[0][0] += gc01 * g.x;  cr[0][1] += gc23 * g.x;
                cr[1][0] += gc01 * g.y;  cr[1][1] += gc23 * g.y;
                cr[2][0] += gc01 * g.z;  cr[2][1] += gc23 * g.z;
                cr[3][0] += gc01 * g.w;  cr[3][1] += gc23 * g.w;
            }

            // membership (pure arithmetic): rf = max(S'-d^2, NHUGE*d^2); pass <=> min_c rf >= 0
            v2f rm[4][2];
#pragma unroll
            for (int c = 0; c < 3; ++c) {
                const float4 e4 = js[9 + c];
                const float4 w4 = js[12 + c];
                const float ejs[4] = {e4.x, e4.y, e4.z, e4.w};
                const float vjs[4] = {w4.x, w4.y, w4.z, w4.w};
#pragma unroll
                for (int tt = 0; tt < 4; ++tt) {
#pragma unroll
                    for (int hf = 0; hf < 2; ++hf) {
                        const v2f d  = eiP[c][hf] - ejs[tt];
                        const v2f S  = viP[c][hf] + vjs[tt];
                        const v2f dd = d * d;
                        const v2f r  = S - dd;
                        const v2f z  = dd * NHUGE;
                        const v2f rf = __builtin_elementwise_max(r, z);
                        rm[tt][hf] = (c == 0) ? rf
                                   : __builtin_elementwise_min(rm[tt][hf], rf);
                    }
                }
            }

            // weights + accumulate
            v2f f01[4], f23[4];
#pragma unroll
            for (int tt = 0; tt < 4; ++tt) {
                const float qjt = qj2[tt >> 1][tt & 1];
                const v2f a0 = cr[tt][0] * 2.f + (nqc[0] - qjt);
                const v2f a1 = cr[tt][1] * 2.f + (nqc[1] - qjt);
                float fv[4];
#pragma unroll
                for (int t = 0; t < 4; ++t) {
                    const bool valid = (tt - t <= 2) && (t - tt <= 2);
                    if (valid) {
                        const float av = (t < 2) ? a0[t & 1] : a1[t & 1];
                        const float rv = (t < 2) ? rm[tt][0][t & 1] : rm[tt][1][t & 1];
                        const float e  = __expf(av);
                        fv[t] = (rv >= 0.f) ? e : 0.f;
                    } else {
                        fv[t] = 0.f;
                    }
                }
                f01[tt] = (v2f){fv[0], fv[1]};
                f23[tt] = (v2f){fv[2], fv[3]};
                denP[0] += f01[tt];
                denP[1] += f23[tt];
            }
#pragma unroll
            for (int c = 0; c < 3; ++c) {
                const float4 n4 = js[15 + c];
                const float njs[4] = {n4.x, n4.y, n4.z, n4.w};
#pragma unroll
                for (int tt = 0; tt < 4; ++tt) {
                    accP[c][0] += f01[tt] * njs[tt];
                    accP[c][1] += f23[tt] * njs[tt];
                }
            }
        }
    }

    // ---- two-phase reduce of 16 slices; reuse halo LDS (8*64*17 floats = 34.8 KB) ----
    __syncthreads();                       // all halo reads complete before overwrite
    float* red = reinterpret_cast<float*>(halo);

    if (s >= 8) {                          // phase 1: upper slices publish
        float* r = red + ((s - 8) * 64 + p) * 17;
#pragma unroll
        for (int c = 0; c < 3; ++c) {
            r[c * 4 + 0] = accP[c][0][0]; r[c * 4 + 1] = accP[c][0][1];
            r[c * 4 + 2] = accP[c][1][0]; r[c * 4 + 3] = accP[c][1][1];
        }
        r[12] = denP[0][0]; r[13] = denP[0][1];
        r[14] = denP[1][0]; r[15] = denP[1][1];
    }
    __syncthreads();

    if (s < 8) {                           // phase 2: lower slices absorb partner, republish
        float* r = red + (s * 64 + p) * 17;
        accP[0][0][0] += r[0];  accP[0][0][1] += r[1];
        accP[0][1][0] += r[2];  accP[0][1][1] += r[3];
        accP[1][0][0] += r[4];  accP[1][0][1] += r[5];
        accP[1][1][0] += r[6];  accP[1][1][1] += r[7];
        accP[2][0][0] += r[8];  accP[2][0][1] += r[9];
        accP[2][1][0] += r[10]; accP[2][1][1] += r[11];
        denP[0][0] += r[12]; denP[0][1] += r[13];
        denP[1][0] += r[14]; denP[1][1] += r[15];
#pragma unroll
        for (int c = 0; c < 3; ++c) {
            r[c * 4 + 0] = accP[c][0][0]; r[c * 4 + 1] = accP[c][0][1];
            r[c * 4 + 2] = accP[c][1][0]; r[c * 4 + 3] = accP[c][1][1];
        }
        r[12] = denP[0][0]; r[13] = denP[0][1];
        r[14] = denP[1][0]; r[15] = denP[1][1];
    }
    __syncthreads();

    if (tid < 64) {                        // s==0: centers here are this pixel's
        float v[16];
        const float* rp = red + p * 17;
#pragma unroll
        for (int i = 0; i < 16; ++i) v[i] = rp[i];
#pragma unroll
        for (int k = 1; k < 8; ++k) {
            const float* rk = red + (k * 64 + p) * 17;
#pragma unroll
            for (int i = 0; i < 16; ++i) v[i] += rk[i];
        }

        // t-axis zero-padded patches: {2,1,1,2} dk-OOB per t, x25 offsets.
        // member iff all ec==0; bw = exp(-qc~).
        const float cnt[4] = {50.f, 25.f, 25.f, 50.f};
        const float qn[4]  = {nqc[0][0], nqc[0][1], nqc[1][0], nqc[1][1]};
        const float e0[4]  = {eiP[0][0][0], eiP[0][0][1], eiP[0][1][0], eiP[0][1][1]};
        const float e1[4]  = {eiP[1][0][0], eiP[1][0][1], eiP[1][1][0], eiP[1][1][1]};
        const float e2[4]  = {eiP[2][0][0], eiP[2][0][1], eiP[2][1][0], eiP[2][1][1]};
#pragma unroll
        for (int t = 0; t < 4; ++t) {
            const bool allz = (e0[t] == 0.f) && (e1[t] == 0.f) && (e2[t] == 0.f);
            const float f0 = allz ? __expf(qn[t]) : 0.f;
            v[12 + t] += cnt[t] * f0;
        }

#pragma unroll
        for (int t = 0; t < 4; ++t) {
            const float inv = 1.f / fmaxf(v[12 + t], 1e-12f);
            v[0 + t] *= inv; v[4 + t] *= inv; v[8 + t] *= inv;
        }
        const int pid = ((tiler * TR + pr) << 7) + tilec * TC + pc;
#pragma unroll
        for (int c = 0; c < 3; ++c) {
            float4 o;
            o.x = v[c * 4 + 0]; o.y = v[c * 4 + 1];
            o.z = v[c * 4 + 2]; o.w = v[c * 4 + 3];
            out[c * NPIX + pid] = o;
        }
    }
}

} // namespace

extern "C" void kernel_launch(void* const* d_in, const int* in_sizes, int n_in,
                              void* d_out, int out_size, void* d_ws, size_t ws_size,
                              hipStream_t stream)
{
    const float4* noisy = (const float4*)d_in[0];
    const float4* guid  = (const float4*)d_in[1];
    const float4* est   = (const float4*)d_in[2];
    const float4* var   = (const float4*)d_in[3];
    float4* out = (float4*)d_out;

    statden<<<(H / TR) * (W / TC), NTHR, 0, stream>>>(noisy, guid, est, var, out);
}

// Round 12
// 18.090 us; speedup vs baseline: 1.9691x; 1.9691x over previous
//
#include <hip/hip_runtime.h>

typedef float v2f __attribute__((ext_vector_type(2)));

namespace {

constexpr int H = 128, W = 128, NPIX = H * W;
constexpr double GAMMA_Wd = 3.3257199;
constexpr float GAM2 = (float)(GAMMA_Wd * GAMMA_Wd);
constexpr float VBIG  = 1e30f;    // var' sentinel for var==0 (incl. OOB pad)
constexpr float NHUGE = -1e38f;   // d!=0 punishment

constexpr int TR = 4, TC = 16;
constexpr int HR = TR + 4, HC = TC + 4;   // 8 x 20
constexpr int NSITE = HR * HC;            // 160
constexpr int NK = 18;   // 9 guid*sqrt(sig/2*log2e) | 3 est | 3 var' | 3 noisy
constexpr int KP = 19;   // padded site stride in float4
constexpr int NTHR = 256;                 // 64 px x 4 column-slices (4 waves)

// exp2-domain folding: weight = exp2( 2*cross - qc~ - qj~ ) with guidance
// pre-scaled by sqrt(sigma/2 * log2(e)); v_exp_f32 computes 2^x natively.
constexpr double S2LOG2E = 1.2011224087864498;   // sqrt(log2(e))
constexpr float SCA0 = (float)(0.22360679774997896 * S2LOG2E);  // sqrt(0.1/2)*
constexpr float SCA1 = (float)(5.0                 * S2LOG2E);  // sqrt(50/2)*
constexpr float SCA2 = (float)(2.2360679774997896  * S2LOG2E);  // sqrt(10/2)*

__global__ __launch_bounds__(NTHR)
__attribute__((amdgpu_waves_per_eu(2, 8)))   // empirically no-spill combo (R9)
void statden(const float4* __restrict__ noisy,
             const float4* __restrict__ guid,
             const float4* __restrict__ est,
             const float4* __restrict__ var,
             float4* __restrict__ out)
{
    __shared__ float4 halo[NSITE * KP];   // 48640 B; later reused as reduce scratch

    const int tid   = threadIdx.x;
    const int tiler = blockIdx.x >> 3;
    const int tilec = blockIdx.x & 7;
    const int r0 = tiler * TR - 2;
    const int c0 = tilec * TC - 2;

    // ---- stage halo (transforms folded in; zero-pad OOB == reference padding) ----
    for (int u = tid; u < NSITE * NK; u += NTHR) {
        const int k    = u / NSITE;
        const int site = u - k * NSITE;
        const int sr  = site / HC;
        const int scp = site - sr * HC;
        const int gr = r0 + sr;
        const int gc = c0 + scp;
        const bool varslot = (k >= 12) && (k < 15);
        float4 v;
        if (((unsigned)gr < (unsigned)H) && ((unsigned)gc < (unsigned)W)) {
            const int gpix = (gr << 7) + gc;
            if (k < 9) {
                const float sca = (k < 3) ? SCA0 : (k < 6) ? SCA1 : SCA2;
                const float4 g = guid[k * NPIX + gpix];
                v = make_float4(g.x * sca, g.y * sca, g.z * sca, g.w * sca);
            } else if (k < 12) {
                v = est[(k - 9) * NPIX + gpix];
            } else if (k < 15) {
                // var' = (var==0) ? -VBIG : gamma^2 * var
                const float4 w4 = var[(k - 12) * NPIX + gpix];
                v.x = (w4.x == 0.f) ? -VBIG : GAM2 * w4.x;
                v.y = (w4.y == 0.f) ? -VBIG : GAM2 * w4.y;
                v.z = (w4.z == 0.f) ? -VBIG : GAM2 * w4.z;
                v.w = (w4.w == 0.f) ? -VBIG : GAM2 * w4.w;
            } else {
                v = noisy[(k - 15) * NPIX + gpix];
            }
        } else {
            const float pad = varslot ? -VBIG : 0.f;
            v = make_float4(pad, pad, pad, pad);
        }
        halo[site * KP + k] = v;
    }
    __syncthreads();

    // ---- compute: thread = (pixel p, slice s); slice owns cols {s, s+4, ...} ----
    const int p  = tid & 63;
    const int s  = tid >> 6;              // 0..3, wave-uniform
    const int pr = p >> 4;
    const int pc = p & 15;

    const float4* cs = &halo[((pr + 2) * HC + (pc + 2)) * KP];

    v2f gcc[9][2];                        // scaled center guidance, packed over t
    v2f nqc[2] = {{0.f, 0.f}, {0.f, 0.f}};   // -qc~ (log2 units)
#pragma unroll
    for (int c = 0; c < 9; ++c) {
        const float4 g = cs[c];
        gcc[c][0] = (v2f){g.x, g.y};
        gcc[c][1] = (v2f){g.z, g.w};
        nqc[0] -= gcc[c][0] * gcc[c][0];
        nqc[1] -= gcc[c][1] * gcc[c][1];
    }
    v2f eiP[3][2], viP[3][2];
#pragma unroll
    for (int c = 0; c < 3; ++c) {
        const float4 e = cs[9 + c];
        eiP[c][0] = (v2f){e.x, e.y}; eiP[c][1] = (v2f){e.z, e.w};
        const float4 w4 = cs[12 + c];
        viP[c][0] = (v2f){w4.x, w4.y}; viP[c][1] = (v2f){w4.z, w4.w};
    }

    v2f accP[3][2] = {};
    v2f denP[2] = {};

#pragma unroll
    for (int cc = 0; cc < 7; ++cc) {
        const int col = (cc << 2) + s;
        if (col < 25) {                   // wave-uniform (only cc=6 filters)
            const int di = col / 5 - 2;
            const int dj = col - (col / 5) * 5 - 2;
            const float4* js = &halo[((pr + 2 + di) * HC + (pc + 2 + dj)) * KP];

            // guidance quadratic (packed)
            v2f qj2[2] = {};
            v2f cr[4][2] = {};            // cross[tt][t-half]
#pragma unroll
            for (int c = 0; c < 9; ++c) {
                const float4 g = js[c];
                const v2f g01 = (v2f){g.x, g.y}, g23 = (v2f){g.z, g.w};
                qj2[0] += g01 * g01;  qj2[1] += g23 * g23;
                cr[0][0] += gcc[c][0] * g.x;  cr[0][1] += gcc[c][1] * g.x;
                cr[1][0] += gcc[c][0] * g.y;  cr[1][1] += gcc[c][1] * g.y;
                cr[2][0] += gcc[c][0] * g.z;  cr[2][1] += gcc[c][1] * g.z;
                cr[3][0] += gcc[c][0] * g.w;  cr[3][1] += gcc[c][1] * g.w;
            }

            // membership (pure arithmetic): rf = max(S'-d^2, NHUGE*d^2); pass <=> min_c rf >= 0
            v2f rm[4][2];
#pragma unroll
            for (int c = 0; c < 3; ++c) {
                const float4 e4 = js[9 + c];
                const float4 w4 = js[12 + c];
                const float ejs[4] = {e4.x, e4.y, e4.z, e4.w};
                const float vjs[4] = {w4.x, w4.y, w4.z, w4.w};
#pragma unroll
                for (int tt = 0; tt < 4; ++tt) {
#pragma unroll
                    for (int hf = 0; hf < 2; ++hf) {
                        const v2f d  = eiP[c][hf] - ejs[tt];
                        const v2f S  = viP[c][hf] + vjs[tt];
                        const v2f dd = d * d;
                        const v2f r  = S - dd;
                        const v2f z  = dd * NHUGE;
                        const v2f rf = __builtin_elementwise_max(r, z);
                        rm[tt][hf] = (c == 0) ? rf
                                   : __builtin_elementwise_min(rm[tt][hf], rf);
                    }
                }
            }

            // weights + accumulate (exp2 domain)
            v2f f01[4], f23[4];
#pragma unroll
            for (int tt = 0; tt < 4; ++tt) {
                const float qjt = qj2[tt >> 1][tt & 1];
                const v2f a0 = cr[tt][0] * 2.f + (nqc[0] - qjt);
                const v2f a1 = cr[tt][1] * 2.f + (nqc[1] - qjt);
                float fv[4];
#pragma unroll
                for (int t = 0; t < 4; ++t) {
                    const bool valid = (tt - t <= 2) && (t - tt <= 2);
                    if (valid) {
                        const float av = (t < 2) ? a0[t & 1] : a1[t & 1];
                        const float rv = (t < 2) ? rm[tt][0][t & 1] : rm[tt][1][t & 1];
                        const float e  = __builtin_exp2f(av);
                        fv[t] = (rv >= 0.f) ? e : 0.f;
                    } else {
                        fv[t] = 0.f;
                    }
                }
                f01[tt] = (v2f){fv[0], fv[1]};
                f23[tt] = (v2f){fv[2], fv[3]};
                denP[0] += f01[tt];
                denP[1] += f23[tt];
            }
#pragma unroll
            for (int c = 0; c < 3; ++c) {
                const float4 n4 = js[15 + c];
                const float njs[4] = {n4.x, n4.y, n4.z, n4.w};
#pragma unroll
                for (int tt = 0; tt < 4; ++tt) {
                    accP[c][0] += f01[tt] * njs[tt];
                    accP[c][1] += f23[tt] * njs[tt];
                }
            }
        }
    }

    // ---- reduce 4 slices; reuse halo LDS as float scratch (stride 17) ----
    __syncthreads();                       // all halo reads complete before overwrite
    float* red = reinterpret_cast<float*>(halo);
    {
        float* r = red + (s * 64 + p) * 17;
#pragma unroll
        for (int c = 0; c < 3; ++c) {
            r[c * 4 + 0] = accP[c][0][0]; r[c * 4 + 1] = accP[c][0][1];
            r[c * 4 + 2] = accP[c][1][0]; r[c * 4 + 3] = accP[c][1][1];
        }
        r[12] = denP[0][0]; r[13] = denP[0][1];
        r[14] = denP[1][0]; r[15] = denP[1][1];
    }
    __syncthreads();

    if (tid < 64) {                        // s==0: centers here are this pixel's
        float v[16];
        const float* rp = red + p * 17;
#pragma unroll
        for (int i = 0; i < 16; ++i) v[i] = rp[i];
#pragma unroll
        for (int k = 1; k < 4; ++k) {
            const float* rk = red + (k * 64 + p) * 17;
#pragma unroll
            for (int i = 0; i < 16; ++i) v[i] += rk[i];
        }

        // t-axis zero-padded patches: {2,1,1,2} dk-OOB per t, x25 offsets.
        // member iff all ec==0; bw = exp2(-qc~) (qc~ already in log2 units).
        const float cnt[4] = {50.f, 25.f, 25.f, 50.f};
        const float qn[4]  = {nqc[0][0], nqc[0][1], nqc[1][0], nqc[1][1]};
        const float e0[4]  = {eiP[0][0][0], eiP[0][0][1], eiP[0][1][0], eiP[0][1][1]};
        const float e1[4]  = {eiP[1][0][0], eiP[1][0][1], eiP[1][1][0], eiP[1][1][1]};
        const float e2[4]  = {eiP[2][0][0], eiP[2][0][1], eiP[2][1][0], eiP[2][1][1]};
#pragma unroll
        for (int t = 0; t < 4; ++t) {
            const bool allz = (e0[t] == 0.f) && (e1[t] == 0.f) && (e2[t] == 0.f);
            const float f0 = allz ? __builtin_exp2f(qn[t]) : 0.f;
            v[12 + t] += cnt[t] * f0;
        }

#pragma unroll
        for (int t = 0; t < 4; ++t) {
            const float inv = 1.f / fmaxf(v[12 + t], 1e-12f);
            v[0 + t] *= inv; v[4 + t] *= inv; v[8 + t] *= inv;
        }
        const int pid = ((tiler * TR + pr) << 7) + tilec * TC + pc;
#pragma unroll
        for (int c = 0; c < 3; ++c) {
            float4 o;
            o.x = v[c * 4 + 0]; o.y = v[c * 4 + 1];
            o.z = v[c * 4 + 2]; o.w = v[c * 4 + 3];
            out[c * NPIX + pid] = o;
        }
    }
}

} // namespace

extern "C" void kernel_launch(void* const* d_in, const int* in_sizes, int n_in,
                              void* d_out, int out_size, void* d_ws, size_t ws_size,
                              hipStream_t stream)
{
    const float4* noisy = (const float4*)d_in[0];
    const float4* guid  = (const float4*)d_in[1];
    const float4* est   = (const float4*)d_in[2];
    const float4* var   = (const float4*)d_in[3];
    float4* out = (float4*)d_out;

    statden<<<(H / TR) * (W / TC), NTHR, 0, stream>>>(noisy, guid, est, var, out);
}

// Round 13
// 18.088 us; speedup vs baseline: 1.9693x; 1.0001x over previous
//
#include <hip/hip_runtime.h>

typedef float v2f __attribute__((ext_vector_type(2)));

namespace {

constexpr int H = 128, W = 128, NPIX = H * W;
constexpr double GAMMA_Wd = 3.3257199;
constexpr float GAM2 = (float)(GAMMA_Wd * GAMMA_Wd);
constexpr float VBIG  = 1e30f;    // var' sentinel for var==0 (incl. OOB pad)
constexpr float NHUGE = -1e38f;   // d!=0 punishment

constexpr int TR = 4, TC = 16;
constexpr int HR = TR + 4, HC = TC + 4;   // 8 x 20
constexpr int NSITE = HR * HC;            // 160
constexpr int NK = 18;   // 9 guid*sqrt(sig/2*log2e) | 3 est | 3 var' | 3 noisy
constexpr int KP = 19;   // padded site stride in float4
constexpr int NSL = 12;                   // column-slices (waves)
constexpr int NTHR = 64 * NSL;            // 768 threads = 12 waves

// exp2-domain folding: weight = exp2( 2*cross - qc~ - qj~ ) with guidance
// pre-scaled by sqrt(sigma/2 * log2(e)); v_exp_f32 computes 2^x natively.
constexpr double S2LOG2E = 1.2011224087864498;   // sqrt(log2(e))
constexpr float SCA0 = (float)(0.22360679774997896 * S2LOG2E);
constexpr float SCA1 = (float)(5.0                 * S2LOG2E);
constexpr float SCA2 = (float)(2.2360679774997896  * S2LOG2E);

// 12 waves/block, grid=256 (1 block/CU) -> 3 waves/SIMD. waves_per_eu(3,4)
// pins the allocator target: cap = 512/3 = 170 VGPR >= body demand (~155),
// and stops the LDS-derived heuristic that throttled 640-thr builds to 84
// VGPR (rounds 3/5/6: 140 MB scratch traffic).
__global__ __launch_bounds__(NTHR)
__attribute__((amdgpu_waves_per_eu(3, 4)))
void statden(const float4* __restrict__ noisy,
             const float4* __restrict__ guid,
             const float4* __restrict__ est,
             const float4* __restrict__ var,
             float4* __restrict__ out)
{
    // max(halo 160*19 float4 = 48640 B, reduce 12*64*17 floats = 52224 B)
    __shared__ float shmem[NSL * 64 * 17];
    float4* halo = reinterpret_cast<float4*>(shmem);

    const int tid   = threadIdx.x;
    const int tiler = blockIdx.x >> 3;
    const int tilec = blockIdx.x & 7;
    const int r0 = tiler * TR - 2;
    const int c0 = tilec * TC - 2;

    // ---- stage halo (transforms folded in; zero-pad OOB == reference padding) ----
    for (int u = tid; u < NSITE * NK; u += NTHR) {
        const int k    = u / NSITE;
        const int site = u - k * NSITE;
        const int sr  = site / HC;
        const int scp = site - sr * HC;
        const int gr = r0 + sr;
        const int gc = c0 + scp;
        const bool varslot = (k >= 12) && (k < 15);
        float4 v;
        if (((unsigned)gr < (unsigned)H) && ((unsigned)gc < (unsigned)W)) {
            const int gpix = (gr << 7) + gc;
            if (k < 9) {
                const float sca = (k < 3) ? SCA0 : (k < 6) ? SCA1 : SCA2;
                const float4 g = guid[k * NPIX + gpix];
                v = make_float4(g.x * sca, g.y * sca, g.z * sca, g.w * sca);
            } else if (k < 12) {
                v = est[(k - 9) * NPIX + gpix];
            } else if (k < 15) {
                // var' = (var==0) ? -VBIG : gamma^2 * var
                const float4 w4 = var[(k - 12) * NPIX + gpix];
                v.x = (w4.x == 0.f) ? -VBIG : GAM2 * w4.x;
                v.y = (w4.y == 0.f) ? -VBIG : GAM2 * w4.y;
                v.z = (w4.z == 0.f) ? -VBIG : GAM2 * w4.z;
                v.w = (w4.w == 0.f) ? -VBIG : GAM2 * w4.w;
            } else {
                v = noisy[(k - 15) * NPIX + gpix];
            }
        } else {
            const float pad = varslot ? -VBIG : 0.f;
            v = make_float4(pad, pad, pad, pad);
        }
        halo[site * KP + k] = v;
    }
    __syncthreads();

    // ---- compute: thread = (pixel p, slice s); slice owns cols {s, s+12, (24 iff s==0)} ----
    const int p  = tid & 63;
    const int s  = tid >> 6;              // 0..11, wave-uniform
    const int pr = p >> 4;
    const int pc = p & 15;

    const float4* cs = &halo[((pr + 2) * HC + (pc + 2)) * KP];

    v2f gcc[9][2];                        // scaled center guidance, packed over t
    v2f nqc[2] = {{0.f, 0.f}, {0.f, 0.f}};   // -qc~ (log2 units)
#pragma unroll
    for (int c = 0; c < 9; ++c) {
        const float4 g = cs[c];
        gcc[c][0] = (v2f){g.x, g.y};
        gcc[c][1] = (v2f){g.z, g.w};
        nqc[0] -= gcc[c][0] * gcc[c][0];
        nqc[1] -= gcc[c][1] * gcc[c][1];
    }
    v2f eiP[3][2], viP[3][2];
#pragma unroll
    for (int c = 0; c < 3; ++c) {
        const float4 e = cs[9 + c];
        eiP[c][0] = (v2f){e.x, e.y}; eiP[c][1] = (v2f){e.z, e.w};
        const float4 w4 = cs[12 + c];
        viP[c][0] = (v2f){w4.x, w4.y}; viP[c][1] = (v2f){w4.z, w4.w};
    }

    v2f accP[3][2] = {};
    v2f denP[2] = {};

#pragma unroll
    for (int cc = 0; cc < 3; ++cc) {
        const int col = s + cc * NSL;
        if (col < 25) {                   // wave-uniform (cc=2 active iff s==0)
            const int di = col / 5 - 2;
            const int dj = col - (col / 5) * 5 - 2;
            const float4* js = &halo[((pr + 2 + di) * HC + (pc + 2 + dj)) * KP];

            // guidance quadratic (packed)
            v2f qj2[2] = {};
            v2f cr[4][2] = {};            // cross[tt][t-half]
#pragma unroll
            for (int c = 0; c < 9; ++c) {
                const float4 g = js[c];
                const v2f g01 = (v2f){g.x, g.y}, g23 = (v2f){g.z, g.w};
                qj2[0] += g01 * g01;  qj2[1] += g23 * g23;
                cr[0][0] += gcc[c][0] * g.x;  cr[0][1] += gcc[c][1] * g.x;
                cr[1][0] += gcc[c][0] * g.y;  cr[1][1] += gcc[c][1] * g.y;
                cr[2][0] += gcc[c][0] * g.z;  cr[2][1] += gcc[c][1] * g.z;
                cr[3][0] += gcc[c][0] * g.w;  cr[3][1] += gcc[c][1] * g.w;
            }

            // membership (pure arithmetic): rf = max(S'-d^2, NHUGE*d^2); pass <=> min_c rf >= 0
            v2f rm[4][2];
#pragma unroll
            for (int c = 0; c < 3; ++c) {
                const float4 e4 = js[9 + c];
                const float4 w4 = js[12 + c];
                const float ejs[4] = {e4.x, e4.y, e4.z, e4.w};
                const float vjs[4] = {w4.x, w4.y, w4.z, w4.w};
#pragma unroll
                for (int tt = 0; tt < 4; ++tt) {
#pragma unroll
                    for (int hf = 0; hf < 2; ++hf) {
                        const v2f d  = eiP[c][hf] - ejs[tt];
                        const v2f S  = viP[c][hf] + vjs[tt];
                        const v2f dd = d * d;
                        const v2f r  = S - dd;
                        const v2f z  = dd * NHUGE;
                        const v2f rf = __builtin_elementwise_max(r, z);
                        rm[tt][hf] = (c == 0) ? rf
                                   : __builtin_elementwise_min(rm[tt][hf], rf);
                    }
                }
            }

            // weights + accumulate (exp2 domain)
            v2f f01[4], f23[4];
#pragma unroll
            for (int tt = 0; tt < 4; ++tt) {
                const float qjt = qj2[tt >> 1][tt & 1];
                const v2f a0 = cr[tt][0] * 2.f + (nqc[0] - qjt);
                const v2f a1 = cr[tt][1] * 2.f + (nqc[1] - qjt);
                float fv[4];
#pragma unroll
                for (int t = 0; t < 4; ++t) {
                    const bool valid = (tt - t <= 2) && (t - tt <= 2);
                    if (valid) {
                        const float av = (t < 2) ? a0[t & 1] : a1[t & 1];
                        const float rv = (t < 2) ? rm[tt][0][t & 1] : rm[tt][1][t & 1];
                        const float e  = __builtin_exp2f(av);
                        fv[t] = (rv >= 0.f) ? e : 0.f;
                    } else {
                        fv[t] = 0.f;
                    }
                }
                f01[tt] = (v2f){fv[0], fv[1]};
                f23[tt] = (v2f){fv[2], fv[3]};
                denP[0] += f01[tt];
                denP[1] += f23[tt];
            }
#pragma unroll
            for (int c = 0; c < 3; ++c) {
                const float4 n4 = js[15 + c];
                const float njs[4] = {n4.x, n4.y, n4.z, n4.w};
#pragma unroll
                for (int tt = 0; tt < 4; ++tt) {
                    accP[c][0] += f01[tt] * njs[tt];
                    accP[c][1] += f23[tt] * njs[tt];
                }
            }
        }
    }

    // ---- reduce 12 slices; reuse shmem as float scratch (stride 17) ----
    __syncthreads();                       // all halo reads complete before overwrite
    float* red = shmem;
    {
        float* r = red + (s * 64 + p) * 17;
#pragma unroll
        for (int c = 0; c < 3; ++c) {
            r[c * 4 + 0] = accP[c][0][0]; r[c * 4 + 1] = accP[c][0][1];
            r[c * 4 + 2] = accP[c][1][0]; r[c * 4 + 3] = accP[c][1][1];
        }
        r[12] = denP[0][0]; r[13] = denP[0][1];
        r[14] = denP[1][0]; r[15] = denP[1][1];
    }
    __syncthreads();

    if (tid < 64) {                        // s==0: centers here are this pixel's
        float v[16];
        const float* rp = red + p * 17;
#pragma unroll
        for (int i = 0; i < 16; ++i) v[i] = rp[i];
#pragma unroll
        for (int k = 1; k < NSL; ++k) {
            const float* rk = red + (k * 64 + p) * 17;
#pragma unroll
            for (int i = 0; i < 16; ++i) v[i] += rk[i];
        }

        // t-axis zero-padded patches: {2,1,1,2} dk-OOB per t, x25 offsets.
        // member iff all ec==0; bw = exp2(-qc~) (qc~ already in log2 units).
        const float cnt[4] = {50.f, 25.f, 25.f, 50.f};
        const float qn[4]  = {nqc[0][0], nqc[0][1], nqc[1][0], nqc[1][1]};
        const float e0[4]  = {eiP[0][0][0], eiP[0][0][1], eiP[0][1][0], eiP[0][1][1]};
        const float e1[4]  = {eiP[1][0][0], eiP[1][0][1], eiP[1][1][0], eiP[1][1][1]};
        const float e2[4]  = {eiP[2][0][0], eiP[2][0][1], eiP[2][1][0], eiP[2][1][1]};
#pragma unroll
        for (int t = 0; t < 4; ++t) {
            const bool allz = (e0[t] == 0.f) && (e1[t] == 0.f) && (e2[t] == 0.f);
            const float f0 = allz ? __builtin_exp2f(qn[t]) : 0.f;
            v[12 + t] += cnt[t] * f0;
        }

#pragma unroll
        for (int t = 0; t < 4; ++t) {
            const float inv = 1.f / fmaxf(v[12 + t], 1e-12f);
            v[0 + t] *= inv; v[4 + t] *= inv; v[8 + t] *= inv;
        }
        const int pid = ((tiler * TR + pr) << 7) + tilec * TC + pc;
#pragma unroll
        for (int c = 0; c < 3; ++c) {
            float4 o;
            o.x = v[c * 4 + 0]; o.y = v[c * 4 + 1];
            o.z = v[c * 4 + 2]; o.w = v[c * 4 + 3];
            out[c * NPIX + pid] = o;
        }
    }
}

} // namespace

extern "C" void kernel_launch(void* const* d_in, const int* in_sizes, int n_in,
                              void* d_out, int out_size, void* d_ws, size_t ws_size,
                              hipStream_t stream)
{
    const float4* noisy = (const float4*)d_in[0];
    const float4* guid  = (const float4*)d_in[1];
    const float4* est   = (const float4*)d_in[2];
    const float4* var   = (const float4*)d_in[3];
    float4* out = (float4*)d_out;

    statden<<<(H / TR) * (W / TC), NTHR, 0, stream>>>(noisy, guid, est, var, out);
}

// Round 14
// 16.618 us; speedup vs baseline: 2.1436x; 1.0885x over previous
//
#include <hip/hip_runtime.h>

typedef float v2f __attribute__((ext_vector_type(2)));

namespace {

constexpr int H = 128, W = 128, NPIX = H * W;
constexpr double GAMMA_Wd = 3.3257199;
constexpr float GAM2 = (float)(GAMMA_Wd * GAMMA_Wd);
constexpr float VBIG  = 1e30f;    // var' sentinel for var==0 (incl. OOB pad)
constexpr float NHUGE = -1e38f;   // d!=0 punishment

constexpr int TR = 4, TC = 16;
constexpr int HR = TR + 4, HC = TC + 4;   // 8 x 20
constexpr int NSITE = HR * HC;            // 160
constexpr int NK = 18;   // 9 guid*sqrt(sig/2*log2e) | 3 est | 3 var' | 3 noisy
constexpr int KP = 19;   // padded site stride in float4
constexpr int NSL = 8;                    // column-slices (waves)
constexpr int NTHR = 64 * NSL;            // 512

constexpr double S2LOG2E = 1.2011224087864498;   // sqrt(log2(e))
constexpr float SCA0 = (float)(0.22360679774997896 * S2LOG2E);
constexpr float SCA1 = (float)(5.0                 * S2LOG2E);
constexpr float SCA2 = (float)(2.2360679774997896  * S2LOG2E);

// Packed per-column body shared by main loop and tail (center column).
// Branchless; all indices compile-time.
__device__ __forceinline__ void column_body(
    const float4* __restrict__ js,
    const v2f gcc[9][2], const v2f nqc[2],
    const v2f eiP[3][2], const v2f viP[3][2],
    v2f accP[3][2], v2f denP[2])
{
    // guidance quadratic (packed)
    v2f qj2[2] = {};
    v2f cr[4][2] = {};            // cross[tt][t-half]
#pragma unroll
    for (int c = 0; c < 9; ++c) {
        const float4 g = js[c];
        const v2f g01 = (v2f){g.x, g.y}, g23 = (v2f){g.z, g.w};
        qj2[0] += g01 * g01;  qj2[1] += g23 * g23;
        cr[0][0] += gcc[c][0] * g.x;  cr[0][1] += gcc[c][1] * g.x;
        cr[1][0] += gcc[c][0] * g.y;  cr[1][1] += gcc[c][1] * g.y;
        cr[2][0] += gcc[c][0] * g.z;  cr[2][1] += gcc[c][1] * g.z;
        cr[3][0] += gcc[c][0] * g.w;  cr[3][1] += gcc[c][1] * g.w;
    }

    // membership (pure arithmetic): rf = max(S'-d^2, NHUGE*d^2); pass <=> min_c rf >= 0
    v2f rm[4][2];
#pragma unroll
    for (int c = 0; c < 3; ++c) {
        const float4 e4 = js[9 + c];
        const float4 w4 = js[12 + c];
        const float ejs[4] = {e4.x, e4.y, e4.z, e4.w};
        const float vjs[4] = {w4.x, w4.y, w4.z, w4.w};
#pragma unroll
        for (int tt = 0; tt < 4; ++tt) {
#pragma unroll
            for (int hf = 0; hf < 2; ++hf) {
                const v2f d  = eiP[c][hf] - ejs[tt];
                const v2f S  = viP[c][hf] + vjs[tt];
                const v2f dd = d * d;
                const v2f r  = S - dd;
                const v2f z  = dd * NHUGE;
                const v2f rf = __builtin_elementwise_max(r, z);
                rm[tt][hf] = (c == 0) ? rf
                           : __builtin_elementwise_min(rm[tt][hf], rf);
            }
        }
    }

    // weights + accumulate (exp2 domain)
    v2f f01[4], f23[4];
#pragma unroll
    for (int tt = 0; tt < 4; ++tt) {
        const float qjt = qj2[tt >> 1][tt & 1];
        const v2f a0 = cr[tt][0] * 2.f + (nqc[0] - qjt);
        const v2f a1 = cr[tt][1] * 2.f + (nqc[1] - qjt);
        float fv[4];
#pragma unroll
        for (int t = 0; t < 4; ++t) {
            const bool valid = (tt - t <= 2) && (t - tt <= 2);
            if (valid) {
                const float av = (t < 2) ? a0[t & 1] : a1[t & 1];
                const float rv = (t < 2) ? rm[tt][0][t & 1] : rm[tt][1][t & 1];
                const float e  = __builtin_exp2f(av);
                fv[t] = (rv >= 0.f) ? e : 0.f;
            } else {
                fv[t] = 0.f;
            }
        }
        f01[tt] = (v2f){fv[0], fv[1]};
        f23[tt] = (v2f){fv[2], fv[3]};
        denP[0] += f01[tt];
        denP[1] += f23[tt];
    }
#pragma unroll
    for (int c = 0; c < 3; ++c) {
        const float4 n4 = js[15 + c];
        const float njs[4] = {n4.x, n4.y, n4.z, n4.w};
#pragma unroll
        for (int tt = 0; tt < 4; ++tt) {
            accP[c][0] += f01[tt] * njs[tt];
            accP[c][1] += f23[tt] * njs[tt];
        }
    }
}

__global__ __launch_bounds__(NTHR)
__attribute__((amdgpu_waves_per_eu(2, 8)))   // empirically no-spill combo (R9)
void statden(const float4* __restrict__ noisy,
             const float4* __restrict__ guid,
             const float4* __restrict__ est,
             const float4* __restrict__ var,
             float4* __restrict__ out)
{
    // Separate regions: halo stays intact through the tail (center column
    // is computed there); grid == #CUs so 83.4 KB LDS costs no occupancy.
    __shared__ float4 halo[NSITE * KP];       // 48640 B
    __shared__ float  red[NSL * 64 * 17];     // 34816 B

    const int tid   = threadIdx.x;
    const int tiler = blockIdx.x >> 3;
    const int tilec = blockIdx.x & 7;
    const int r0 = tiler * TR - 2;
    const int c0 = tilec * TC - 2;

    // ---- stage halo (transforms folded in; zero-pad OOB == reference padding) ----
    for (int u = tid; u < NSITE * NK; u += NTHR) {
        const int k    = u / NSITE;
        const int site = u - k * NSITE;
        const int sr  = site / HC;
        const int scp = site - sr * HC;
        const int gr = r0 + sr;
        const int gc = c0 + scp;
        const bool varslot = (k >= 12) && (k < 15);
        float4 v;
        if (((unsigned)gr < (unsigned)H) && ((unsigned)gc < (unsigned)W)) {
            const int gpix = (gr << 7) + gc;
            if (k < 9) {
                const float sca = (k < 3) ? SCA0 : (k < 6) ? SCA1 : SCA2;
                const float4 g = guid[k * NPIX + gpix];
                v = make_float4(g.x * sca, g.y * sca, g.z * sca, g.w * sca);
            } else if (k < 12) {
                v = est[(k - 9) * NPIX + gpix];
            } else if (k < 15) {
                const float4 w4 = var[(k - 12) * NPIX + gpix];
                v.x = (w4.x == 0.f) ? -VBIG : GAM2 * w4.x;
                v.y = (w4.y == 0.f) ? -VBIG : GAM2 * w4.y;
                v.z = (w4.z == 0.f) ? -VBIG : GAM2 * w4.z;
                v.w = (w4.w == 0.f) ? -VBIG : GAM2 * w4.w;
            } else {
                v = noisy[(k - 15) * NPIX + gpix];
            }
        } else {
            const float pad = varslot ? -VBIG : 0.f;
            v = make_float4(pad, pad, pad, pad);
        }
        halo[site * KP + k] = v;
    }
    __syncthreads();

    // ---- compute: thread = (pixel p, slice s); slice s owns 3 of the 24
    //      non-center columns (center col 12 is done in the tail) ----
    const int p  = tid & 63;
    const int s  = tid >> 6;              // 0..7, wave-uniform
    const int pr = p >> 4;
    const int pc = p & 15;

    const float4* cs = &halo[((pr + 2) * HC + (pc + 2)) * KP];

    v2f gcc[9][2];
    v2f nqc[2] = {{0.f, 0.f}, {0.f, 0.f}};   // -qc~ (log2 units)
#pragma unroll
    for (int c = 0; c < 9; ++c) {
        const float4 g = cs[c];
        gcc[c][0] = (v2f){g.x, g.y};
        gcc[c][1] = (v2f){g.z, g.w};
        nqc[0] -= gcc[c][0] * gcc[c][0];
        nqc[1] -= gcc[c][1] * gcc[c][1];
    }
    v2f eiP[3][2], viP[3][2];
#pragma unroll
    for (int c = 0; c < 3; ++c) {
        const float4 e = cs[9 + c];
        eiP[c][0] = (v2f){e.x, e.y}; eiP[c][1] = (v2f){e.z, e.w};
        const float4 w4 = cs[12 + c];
        viP[c][0] = (v2f){w4.x, w4.y}; viP[c][1] = (v2f){w4.z, w4.w};
    }

    v2f accP[3][2] = {};
    v2f denP[2] = {};

    // BRANCHLESS: every slice runs exactly 3 columns, fully unrolled, so the
    // scheduler can issue column k+1's ds_reads under column k's compute.
#pragma unroll
    for (int mm = 0; mm < 3; ++mm) {
        const int m   = s * 3 + mm;
        const int col = m + (m >= 12 ? 1 : 0);   // skip center (col 12)
        const int di  = col / 5 - 2;
        const int dj  = col - (col / 5) * 5 - 2;
        const float4* js = &halo[((pr + 2 + di) * HC + (pc + 2 + dj)) * KP];
        column_body(js, gcc, nqc, eiP, viP, accP, denP);
    }

    // ---- publish slice partials ----
    {
        float* r = red + (s * 64 + p) * 17;
#pragma unroll
        for (int c = 0; c < 3; ++c) {
            r[c * 4 + 0] = accP[c][0][0]; r[c * 4 + 1] = accP[c][0][1];
            r[c * 4 + 2] = accP[c][1][0]; r[c * 4 + 3] = accP[c][1][1];
        }
        r[12] = denP[0][0]; r[13] = denP[0][1];
        r[14] = denP[1][0]; r[15] = denP[1][1];
    }
    __syncthreads();

    if (tid < 64) {                        // s==0: centers here are this pixel's
        float v[16];
        const float* rp = red + p * 17;
#pragma unroll
        for (int i = 0; i < 16; ++i) v[i] = rp[i];
#pragma unroll
        for (int k = 1; k < NSL; ++k) {
            const float* rk = red + (k * 64 + p) * 17;
#pragma unroll
            for (int i = 0; i < 16; ++i) v[i] += rk[i];
        }

        // center column (di=dj=0): halo is intact (red is a separate region)
        {
            v2f accC[3][2] = {};
            v2f denC[2] = {};
            column_body(cs, gcc, nqc, eiP, viP, accC, denC);
#pragma unroll
            for (int c = 0; c < 3; ++c) {
                v[c * 4 + 0] += accC[c][0][0]; v[c * 4 + 1] += accC[c][0][1];
                v[c * 4 + 2] += accC[c][1][0]; v[c * 4 + 3] += accC[c][1][1];
            }
            v[12] += denC[0][0]; v[13] += denC[0][1];
            v[14] += denC[1][0]; v[15] += denC[1][1];
        }

        // t-axis zero-padded patches: {2,1,1,2} dk-OOB per t, x25 offsets.
        const float cnt[4] = {50.f, 25.f, 25.f, 50.f};
        const float qn[4]  = {nqc[0][0], nqc[0][1], nqc[1][0], nqc[1][1]};
        const float e0[4]  = {eiP[0][0][0], eiP[0][0][1], eiP[0][1][0], eiP[0][1][1]};
        const float e1[4]  = {eiP[1][0][0], eiP[1][0][1], eiP[1][1][0], eiP[1][1][1]};
        const float e2[4]  = {eiP[2][0][0], eiP[2][0][1], eiP[2][1][0], eiP[2][1][1]};
#pragma unroll
        for (int t = 0; t < 4; ++t) {
            const bool allz = (e0[t] == 0.f) && (e1[t] == 0.f) && (e2[t] == 0.f);
            const float f0 = allz ? __builtin_exp2f(qn[t]) : 0.f;
            v[12 + t] += cnt[t] * f0;
        }

#pragma unroll
        for (int t = 0; t < 4; ++t) {
            const float inv = 1.f / fmaxf(v[12 + t], 1e-12f);
            v[0 + t] *= inv; v[4 + t] *= inv; v[8 + t] *= inv;
        }
        const int pid = ((tiler * TR + pr) << 7) + tilec * TC + pc;
#pragma unroll
        for (int c = 0; c < 3; ++c) {
            float4 o;
            o.x = v[c * 4 + 0]; o.y = v[c * 4 + 1];
            o.z = v[c * 4 + 2]; o.w = v[c * 4 + 3];
            out[c * NPIX + pid] = o;
        }
    }
}

} // namespace

extern "C" void kernel_launch(void* const* d_in, const int* in_sizes, int n_in,
                              void* d_out, int out_size, void* d_ws, size_t ws_size,
                              hipStream_t stream)
{
    const float4* noisy = (const float4*)d_in[0];
    const float4* guid  = (const float4*)d_in[1];
    const float4* est   = (const float4*)d_in[2];
    const float4* var   = (const float4*)d_in[3];
    float4* out = (float4*)d_out;

    statden<<<(H / TR) * (W / TC), NTHR, 0, stream>>>(noisy, guid, est, var, out);
}